// Round 5
// baseline (77.942 us; speedup 1.0000x reference)
//
#include <hip/hip_runtime.h>
#include <math.h>

#define DD 8
#define MM 7
#define MOO 9
#define NPTS 100
#define EPSF 1e-5f

#define THREADS 512
#define ITERS 16          // THREADS*4*ITERS == 32768 rules
#define CAP 256           // candidate buffer capacity per row
#define NBUCK 4096        // hi-12-bit buckets

// ---------------- pack+hist: antecedents -> offset word + bucket histogram --
// w = ((code & 4095) << 3) | ((code >> 12) << 19)
//   lo 16 bits: byte offset into float2 quad table 0 (dims 0-3)
//   hi 16 bits: byte offset into float2 quad table 1 (dims 4-7)
//   bucket id = w >> 19. g_hist must be zeroed before this kernel.
__global__ __launch_bounds__(256) void pack_hist_kernel(const int* __restrict__ ant,
                                                        unsigned* __restrict__ g_off,
                                                        unsigned* __restrict__ g_hist,
                                                        int R) {
    int r = blockIdx.x * 256 + threadIdx.x;
    if (r < R) {
        const int4* a = reinterpret_cast<const int4*>(ant) + (size_t)r * 2;
        int4 lo = a[0], hi = a[1];
        int v[8] = {lo.x, lo.y, lo.z, lo.w, hi.x, hi.y, hi.z, hi.w};
        unsigned code = 0u;
        #pragma unroll
        for (int i = 0; i < 8; ++i) {
            int c = v[i];
            c = (c < 0) ? 7 : (c > MM - 1 ? MM - 1 : c);   // -1 -> wildcard slot 7
            code |= (unsigned)c << (3 * i);
        }
        g_off[r] = ((code & 4095u) << 3) | ((code >> 12) << 19);
        atomicAdd(&g_hist[code >> 12], 1u);
    }
}

// ---------------- scan: one block, in-place hist -> exclusive bucket bases --
__global__ __launch_bounds__(1024) void scan_kernel(unsigned* __restrict__ g_hist) {
    __shared__ unsigned aux[1024];
    const int tid = threadIdx.x;
    unsigned h0 = g_hist[4 * tid],     h1 = g_hist[4 * tid + 1];
    unsigned h2 = g_hist[4 * tid + 2], h3 = g_hist[4 * tid + 3];
    aux[tid] = h0 + h1 + h2 + h3;
    __syncthreads();
    for (int off = 1; off < 1024; off <<= 1) {
        unsigned v = (tid >= off) ? aux[tid - off] : 0u;
        __syncthreads();
        aux[tid] += v;
        __syncthreads();
    }
    unsigned base = tid ? aux[tid - 1] : 0u;
    g_hist[4 * tid]     = base;
    g_hist[4 * tid + 1] = base + h0;
    g_hist[4 * tid + 2] = base + h0 + h1;
    g_hist[4 * tid + 3] = base + h0 + h1 + h2;
}

// ---------------- scatter: parallel bucket placement + wave permutation -----
// Rank q lands at p so each main-kernel wave-instruction reads 64 CONSECUTIVE
// sorted rules (hi-table -> ~8-word broadcast runs). Atomic order within a
// bucket is arbitrary -- harmless (final selection uses original index).
__global__ __launch_bounds__(256) void scatter_kernel(const unsigned* __restrict__ g_off,
                                                      unsigned* __restrict__ g_base,
                                                      unsigned* __restrict__ g_soff,
                                                      int* __restrict__ g_sidx,
                                                      int R) {
    int r = blockIdx.x * 256 + threadIdx.x;
    if (r < R) {
        unsigned w = g_off[r];
        unsigned q = atomicAdd(&g_base[w >> 19], 1u);
        unsigned p = (q & ~255u) | ((q & 63u) << 2) | ((q >> 6) & 3u);
        g_soff[p] = w;
        g_sidx[p] = r;
    }
}

// ---------------- main kernel: one block (512 thr) per PAIR of batch rows ---
// Tables hold float2 {row0, row1}: one ds_read_b64 serves both rows at the
// same index -> per (row,rule) DS cost halves; code stream amortizes x2.
__global__ __launch_bounds__(THREADS, 4) void anfis2(
    const float* __restrict__ x,
    const unsigned* __restrict__ stream_off,
    const int* __restrict__ g_sidx,
    const int* __restrict__ consequents,
    const float* __restrict__ in_centers,   // [D][M]
    const float* __restrict__ in_widths,    // [D][M]
    const float* __restrict__ out_centers,  // [MO]
    const float* __restrict__ out_widths,   // [MO]
    float* __restrict__ out)
{
    __shared__ float   mu[2][64];        // [row][d*8+c], c==7 -> 1.0
    __shared__ float   pairs[2][256];    // [row][4 tables x 64]
    __shared__ float2  quads2[8192];     // 2 tables x 4096, {row0,row1}
    __shared__ float   s0s[MOO], s1s[MOO];
    __shared__ float2  smax2[THREADS];
    __shared__ float   sthr[2];
    __shared__ int     scnt[2];
    __shared__ float   cvals[2][CAP];
    __shared__ int     cidx[2][CAP];
    __shared__ float   wv[2][8];
    __shared__ int     wc[2][8];

    const int tid = threadIdx.x;
    const int b0  = blockIdx.x * 2;

    // --- phase 0: membership tables (both rows) + defuzz constants ---
    if (tid < 128) {
        int row = tid >> 6, d = (tid >> 3) & 7, c = tid & 7;
        float v = 1.0f;
        if (c < MM) {
            float z = (x[(b0 + row) * DD + d] - in_centers[d * MM + c]) / in_widths[d * MM + c];
            v = expf(-0.5f * z * z);
            v = fminf(v, 1.0f);
            v = fmaxf(v, EPSF);
        }
        mu[row][(d << 3) + c] = v;
    } else if (tid < 128 + MOO) {
        int mo = tid - 128;
        float oc = out_centers[mo], ow = out_widths[mo];
        float s0 = 0.0f, s1 = 0.0f;
        for (int p = 0; p < NPTS; ++p) {
            float u = (float)p * (1.0f / 99.0f);
            float z = (u - oc) / ow;
            float e = expf(-0.5f * z * z);
            s0 += e;
            s1 += u * e;
        }
        s0s[mo] = s0;
        s1s[mo] = s1;
    }
    __syncthreads();

    // --- phase 1: pair products, both rows (512 entries total) ---
    {
        int row = tid >> 8, e = tid & 255;
        int p = e >> 6, q = e & 63;
        pairs[row][e] = mu[row][(2 * p) * 8 + (q & 7)] * mu[row][(2 * p + 1) * 8 + (q >> 3)];
    }
    if (tid == 0) { scnt[0] = 0; scnt[1] = 0; }
    __syncthreads();

    // --- phase 2: quad product tables as float2 {row0,row1} ---
    #pragma unroll
    for (int k = tid; k < 8192; k += THREADS) {
        int t = k & 4095, h = k >> 12;       // h in {0,1}
        float v0 = pairs[0][h * 128 + (t & 63)] * pairs[0][h * 128 + 64 + ((t >> 6) & 63)];
        float v1 = pairs[1][h * 128 + (t & 63)] * pairs[1][h * 128 + 64 + ((t >> 6) & 63)];
        quads2[k] = make_float2(v0, v1);
    }
    __syncthreads();

    // --- phase 3: evaluate all rules for both rows, track per-thread maxes ---
    const uint4* pk4 = reinterpret_cast<const uint4*>(stream_off);
    const char* qb = (const char*)quads2;
    float mymax0 = -1.0f, mymax1 = -1.0f;
    {
        uint4 buf[3];
        buf[0] = pk4[tid];
        buf[1] = pk4[THREADS + tid];
        #pragma unroll
        for (int j = 0; j < ITERS; ++j) {
            uint4 cd = buf[j % 3];
            if (j + 2 < ITERS) buf[(j + 2) % 3] = pk4[(j + 2) * THREADS + tid];
            unsigned cods[4] = {cd.x, cd.y, cd.z, cd.w};
            #pragma unroll
            for (int s = 0; s < 4; ++s) {
                unsigned w = cods[s];
                float2 a = *(const float2*)(qb + (w & 0xFFFFu));
                float2 t = *(const float2*)(qb + 32768u + (w >> 16));
                mymax0 = fmaxf(mymax0, a.x * t.x);
                mymax1 = fmaxf(mymax1, a.y * t.y);
            }
        }
    }
    smax2[tid] = make_float2(mymax0, mymax1);
    __syncthreads();

    // --- phase 4: waves 0/1 extract 8th-largest thread max per row ---
    if (tid < 128) {
        int row = tid >> 6, lane = tid & 63;
        float m[8];
        #pragma unroll
        for (int k = 0; k < 8; ++k) {
            float2 s = smax2[lane + 64 * k];
            m[k] = row ? s.y : s.x;
        }
        float thr = -1.0f;
        #pragma unroll
        for (int round = 0; round < 8; ++round) {
            float lm = m[0];
            #pragma unroll
            for (int k = 1; k < 8; ++k) lm = fmaxf(lm, m[k]);
            float wm = lm;
            #pragma unroll
            for (int off = 32; off >= 1; off >>= 1)
                wm = fmaxf(wm, __shfl_xor(wm, off, 64));
            unsigned long long bal = __ballot(lm == wm);
            int first = (int)__ffsll(bal) - 1;
            if (lane == first) {                // remove exactly one instance
                bool done = false;
                #pragma unroll
                for (int k = 0; k < 8; ++k) {
                    bool rm = (!done) && (m[k] == wm);
                    m[k] = rm ? -2.0f : m[k];
                    done = done || rm;
                }
            }
            thr = wm;
        }
        if (lane == 0) sthr[row] = thr;
    }
    __syncthreads();

    // --- phase 5: qualifying threads recompute & push candidates per row ---
    {
        const float thr0 = sthr[0], thr1 = sthr[1];
        if (mymax0 >= thr0 || mymax1 >= thr1) {    // ~16-60 threads of 512
            for (int j = 0; j < ITERS; ++j) {
                uint4 cd = pk4[j * THREADS + tid];
                unsigned cods[4] = {cd.x, cd.y, cd.z, cd.w};
                #pragma unroll
                for (int s = 0; s < 4; ++s) {
                    unsigned w = cods[s];
                    float2 a = *(const float2*)(qb + (w & 0xFFFFu));
                    float2 t = *(const float2*)(qb + 32768u + (w >> 16));
                    float f0 = a.x * t.x, f1 = a.y * t.y;
                    if (f0 >= thr0) {
                        int flat = (j * THREADS + tid) * 4 + s;
                        int pos = atomicAdd(&scnt[0], 1);
                        if (pos < CAP) { cvals[0][pos] = f0; cidx[0][pos] = g_sidx[flat]; }
                    }
                    if (f1 >= thr1) {
                        int flat = (j * THREADS + tid) * 4 + s;
                        int pos = atomicAdd(&scnt[1], 1);
                        if (pos < CAP) { cvals[1][pos] = f1; cidx[1][pos] = g_sidx[flat]; }
                    }
                }
            }
        }
    }
    __syncthreads();

    // --- phase 6: exact rank selection per row (val desc, orig idx asc) ---
    if (tid < 128) {
        int row = tid >> 6, lane = tid & 63;
        int n = scnt[row] < CAP ? scnt[row] : CAP;
        for (int c = lane; c < n; c += 64) {
            float v  = cvals[row][c];
            int   id = cidx[row][c];
            int rk = 0;
            for (int mI = 0; mI < n; ++mI) {
                float vm = cvals[row][mI];
                int   im = cidx[row][mI];
                rk += ((vm > v) || (vm == v && im < id)) ? 1 : 0;
            }
            if (rk < 8) {
                wv[row][rk] = v;
                wc[row][rk] = consequents[id];
            }
        }
    }
    __syncthreads();

    // --- phase 7: defuzzify (one thread per row) ---
    if (tid == 0 || tid == 64) {
        int row = tid >> 6;
        float num = 0.0f, den = 0.0f;
        #pragma unroll
        for (int k = 0; k < 8; ++k) {
            num += wv[row][k] * s1s[wc[row][k]];
            den += wv[row][k] * s0s[wc[row][k]];
        }
        out[b0 + row] = num / (den + EPSF);
    }
}

// ---------------- generic fallback (round-1 kernel, inline pack) ------------
__global__ __launch_bounds__(256) void anfis_kernel(
    const float* __restrict__ x,
    const int* __restrict__ ant,
    const int* __restrict__ consequents,
    const float* __restrict__ in_centers,
    const float* __restrict__ in_widths,
    const float* __restrict__ out_centers,
    const float* __restrict__ out_widths,
    float* __restrict__ out,
    int R)
{
    __shared__ float mu[64];
    __shared__ float pairs[256];
    __shared__ float s0s[MOO], s1s[MOO];
    __shared__ float svals[256][9];
    __shared__ int   sidx[256][9];

    const int tid = threadIdx.x;
    const int b   = blockIdx.x;

    if (tid < 64) {
        int d = tid >> 3, c = tid & 7;
        float v = 1.0f;
        if (c < MM) {
            float z = (x[b * DD + d] - in_centers[d * MM + c]) / in_widths[d * MM + c];
            v = expf(-0.5f * z * z);
            v = fminf(v, 1.0f);
            v = fmaxf(v, EPSF);
        }
        mu[tid] = v;
    } else if (tid < 64 + MOO) {
        int mo = tid - 64;
        float oc = out_centers[mo], ow = out_widths[mo];
        float s0 = 0.0f, s1 = 0.0f;
        for (int p = 0; p < NPTS; ++p) {
            float u = (float)p * (1.0f / 99.0f);
            float z = (u - oc) / ow;
            float e = expf(-0.5f * z * z);
            s0 += e;
            s1 += u * e;
        }
        s0s[mo] = s0;
        s1s[mo] = s1;
    }
    __syncthreads();

    {
        int p = tid >> 6, q = tid & 63;
        pairs[tid] = mu[(2 * p) * 8 + (q & 7)] * mu[(2 * p + 1) * 8 + (q >> 3)];
    }
    __syncthreads();

    float vals[8];
    int   idxs[8];
    #pragma unroll
    for (int k = 0; k < 8; ++k) { vals[k] = -1.0f; idxs[k] = 0x7fffffff; }

    for (int r = tid; r < R; r += 256) {
        const int4* a = reinterpret_cast<const int4*>(ant) + (size_t)r * 2;
        int4 lo = a[0], hi = a[1];
        int v[8] = {lo.x, lo.y, lo.z, lo.w, hi.x, hi.y, hi.z, hi.w};
        unsigned code = 0u;
        #pragma unroll
        for (int i = 0; i < 8; ++i) {
            int c = v[i];
            c = (c < 0) ? 7 : (c > MM - 1 ? MM - 1 : c);
            code |= (unsigned)c << (3 * i);
        }
        float f = pairs[code & 63]
                * pairs[64  + ((code >> 6)  & 63)]
                * pairs[128 + ((code >> 12) & 63)]
                * pairs[192 + ((code >> 18) & 63)];
        if (f > vals[7]) {
            float nv = f; int ni = r;
            #pragma unroll
            for (int k = 0; k < 8; ++k) {
                bool take = nv > vals[k];
                float cv = vals[k]; int ci = idxs[k];
                vals[k] = take ? nv : cv;
                idxs[k] = take ? ni : ci;
                nv = take ? cv : nv;
                ni = take ? ci : ni;
            }
        }
    }

    #pragma unroll
    for (int k = 0; k < 8; ++k) { svals[tid][k] = vals[k]; sidx[tid][k] = idxs[k]; }

    for (int off = 128; off >= 1; off >>= 1) {
        __syncthreads();
        if (tid < off) {
            float ov[8]; int oi[8];
            int pa = 0, pb = 0;
            #pragma unroll
            for (int k = 0; k < 8; ++k) {
                float va = svals[tid][pa];        int ia = sidx[tid][pa];
                float vb = svals[tid + off][pb];  int ib = sidx[tid + off][pb];
                bool ta = (va > vb) || ((va == vb) && (ia < ib));
                ov[k] = ta ? va : vb;
                oi[k] = ta ? ia : ib;
                pa += ta ? 1 : 0;
                pb += ta ? 0 : 1;
            }
            #pragma unroll
            for (int k = 0; k < 8; ++k) { svals[tid][k] = ov[k]; sidx[tid][k] = oi[k]; }
        }
    }
    __syncthreads();

    if (tid == 0) {
        float num = 0.0f, den = 0.0f;
        #pragma unroll
        for (int k = 0; k < 8; ++k) {
            float v = svals[0][k];
            int   c = consequents[sidx[0][k]];
            num += v * s1s[c];
            den += v * s0s[c];
        }
        out[b] = num / (den + EPSF);
    }
}

extern "C" void kernel_launch(void* const* d_in, const int* in_sizes, int n_in,
                              void* d_out, int out_size, void* d_ws, size_t ws_size,
                              hipStream_t stream) {
    const float* x      = (const float*)d_in[0];
    const int*   ant    = (const int*)d_in[1];
    const int*   cons   = (const int*)d_in[2];
    const float* in_c   = (const float*)d_in[3];
    const float* in_w   = (const float*)d_in[4];
    const float* out_c  = (const float*)d_in[5];
    const float* out_w  = (const float*)d_in[6];
    float*       out    = (float*)d_out;

    const int B = in_sizes[0] / DD;
    const int R = in_sizes[1] / DD;

    const bool shape_ok = (R == THREADS * 4 * ITERS) && (B % 2 == 0);
    const size_t need = (size_t)R * 12 + (size_t)NBUCK * 4;    // off+soff+sidx+hist

    if (shape_ok && d_ws && ws_size >= need) {
        unsigned* g_off  = (unsigned*)d_ws;
        unsigned* g_soff = g_off + R;
        int*      g_sidx = (int*)(g_soff + R);
        unsigned* g_hist = (unsigned*)(g_sidx + R);
        hipMemsetAsync(g_hist, 0, NBUCK * sizeof(unsigned), stream);
        pack_hist_kernel<<<(R + 255) / 256, 256, 0, stream>>>(ant, g_off, g_hist, R);
        scan_kernel<<<1, 1024, 0, stream>>>(g_hist);
        scatter_kernel<<<(R + 255) / 256, 256, 0, stream>>>(g_off, g_hist, g_soff, g_sidx, R);
        anfis2<<<B / 2, THREADS, 0, stream>>>(x, g_soff, g_sidx, cons,
                                              in_c, in_w, out_c, out_w, out);
    } else {
        anfis_kernel<<<B, 256, 0, stream>>>(x, ant, cons, in_c, in_w,
                                            out_c, out_w, out, R);
    }
}

// Round 6
// 70.732 us; speedup vs baseline: 1.1019x; 1.1019x over previous
//
#include <hip/hip_runtime.h>
#include <math.h>

#define DD 8
#define MM 7
#define MOO 9
#define NPTS 100
#define EPSF 1e-5f

#define THREADS 1024
#define ITERS 8           // THREADS*4*ITERS == 32768 rules
#define CAP 256           // candidate buffer capacity per row
#define NBUCK 4096        // hi-12-bit buckets

// ---------------- pack+hist: antecedents -> offset word + bucket histogram --
// w = ((code & 4095) << 3) | ((code >> 12) << 19)
//   lo 16 bits: byte offset into float2 quad table 0 (dims 0-3)
//   hi 16 bits: byte offset into float2 quad table 1 (dims 4-7)
//   bucket id = w >> 19. g_hist must be zeroed before this kernel.
__global__ __launch_bounds__(256) void pack_hist_kernel(const int* __restrict__ ant,
                                                        unsigned* __restrict__ g_off,
                                                        unsigned* __restrict__ g_hist,
                                                        int R) {
    int r = blockIdx.x * 256 + threadIdx.x;
    if (r < R) {
        const int4* a = reinterpret_cast<const int4*>(ant) + (size_t)r * 2;
        int4 lo = a[0], hi = a[1];
        int v[8] = {lo.x, lo.y, lo.z, lo.w, hi.x, hi.y, hi.z, hi.w};
        unsigned code = 0u;
        #pragma unroll
        for (int i = 0; i < 8; ++i) {
            int c = v[i];
            c = (c < 0) ? 7 : (c > MM - 1 ? MM - 1 : c);   // -1 -> wildcard slot 7
            code |= (unsigned)c << (3 * i);
        }
        g_off[r] = ((code & 4095u) << 3) | ((code >> 12) << 19);
        atomicAdd(&g_hist[code >> 12], 1u);
    }
}

// ---------------- scan: one block, in-place hist -> exclusive bucket bases --
__global__ __launch_bounds__(1024) void scan_kernel(unsigned* __restrict__ g_hist) {
    __shared__ unsigned aux[1024];
    const int tid = threadIdx.x;
    unsigned h0 = g_hist[4 * tid],     h1 = g_hist[4 * tid + 1];
    unsigned h2 = g_hist[4 * tid + 2], h3 = g_hist[4 * tid + 3];
    aux[tid] = h0 + h1 + h2 + h3;
    __syncthreads();
    for (int off = 1; off < 1024; off <<= 1) {
        unsigned v = (tid >= off) ? aux[tid - off] : 0u;
        __syncthreads();
        aux[tid] += v;
        __syncthreads();
    }
    unsigned base = tid ? aux[tid - 1] : 0u;
    g_hist[4 * tid]     = base;
    g_hist[4 * tid + 1] = base + h0;
    g_hist[4 * tid + 2] = base + h0 + h1;
    g_hist[4 * tid + 3] = base + h0 + h1 + h2;
}

// ---------------- scatter: parallel bucket placement + wave permutation -----
// Rank q lands at p so each main-kernel wave-instruction reads 64 CONSECUTIVE
// sorted rules (hi-table -> ~8-word broadcast runs). Atomic order within a
// bucket is arbitrary -- harmless (final selection uses original index).
__global__ __launch_bounds__(256) void scatter_kernel(const unsigned* __restrict__ g_off,
                                                      unsigned* __restrict__ g_base,
                                                      unsigned* __restrict__ g_soff,
                                                      int* __restrict__ g_sidx,
                                                      int R) {
    int r = blockIdx.x * 256 + threadIdx.x;
    if (r < R) {
        unsigned w = g_off[r];
        unsigned q = atomicAdd(&g_base[w >> 19], 1u);
        unsigned p = (q & ~255u) | ((q & 63u) << 2) | ((q >> 6) & 3u);
        g_soff[p] = w;
        g_sidx[p] = r;
    }
}

// ---------------- main kernel: 1024 threads per PAIR of batch rows ----------
// float2 tables {row0,row1}: one ds_read_b64 serves both rows. 1024-thread
// blocks put 32 waves/CU back on the machine (2 blocks x 16 waves; LDS ~79KB)
// -- R5 showed 16 waves leaves both pipes at ~30% (latency-bound).
__global__ __launch_bounds__(THREADS, 8) void anfis2(
    const float* __restrict__ x,
    const unsigned* __restrict__ stream_off,
    const int* __restrict__ g_sidx,
    const int* __restrict__ consequents,
    const float* __restrict__ in_centers,   // [D][M]
    const float* __restrict__ in_widths,    // [D][M]
    const float* __restrict__ out_centers,  // [MO]
    const float* __restrict__ out_widths,   // [MO]
    float* __restrict__ out)
{
    __shared__ float   mu[2][64];        // [row][d*8+c], c==7 -> 1.0
    __shared__ float   pairs[2][256];    // [row][4 tables x 64]
    __shared__ float2  quads2[8192];     // 2 tables x 4096, {row0,row1}
    __shared__ float   s0s[MOO], s1s[MOO];
    __shared__ float2  smax2[THREADS];
    __shared__ float   sthr[2];
    __shared__ int     scnt[2];
    __shared__ float   cvals[2][CAP];
    __shared__ int     cidx[2][CAP];
    __shared__ float   wv[2][8];
    __shared__ int     wc[2][8];

    const int tid = threadIdx.x;
    const int b0  = blockIdx.x * 2;

    // --- phase 0: membership tables (both rows) + defuzz constants ---
    if (tid < 128) {
        int row = tid >> 6, d = (tid >> 3) & 7, c = tid & 7;
        float v = 1.0f;
        if (c < MM) {
            float z = (x[(b0 + row) * DD + d] - in_centers[d * MM + c]) / in_widths[d * MM + c];
            v = expf(-0.5f * z * z);
            v = fminf(v, 1.0f);
            v = fmaxf(v, EPSF);
        }
        mu[row][(d << 3) + c] = v;
    } else if (tid < 128 + MOO) {
        int mo = tid - 128;
        float oc = out_centers[mo], ow = out_widths[mo];
        float s0 = 0.0f, s1 = 0.0f;
        for (int p = 0; p < NPTS; ++p) {
            float u = (float)p * (1.0f / 99.0f);
            float z = (u - oc) / ow;
            float e = expf(-0.5f * z * z);
            s0 += e;
            s1 += u * e;
        }
        s0s[mo] = s0;
        s1s[mo] = s1;
    }
    __syncthreads();

    // --- phase 1: pair products, both rows (512 entries total) ---
    if (tid < 512) {
        int row = tid >> 8, e = tid & 255;
        int p = e >> 6, q = e & 63;
        pairs[row][e] = mu[row][(2 * p) * 8 + (q & 7)] * mu[row][(2 * p + 1) * 8 + (q >> 3)];
    }
    if (tid == 0) { scnt[0] = 0; scnt[1] = 0; }
    __syncthreads();

    // --- phase 2: quad product tables as float2 {row0,row1} ---
    #pragma unroll
    for (int k = tid; k < 8192; k += THREADS) {
        int t = k & 4095, h = k >> 12;       // h in {0,1}
        float v0 = pairs[0][h * 128 + (t & 63)] * pairs[0][h * 128 + 64 + ((t >> 6) & 63)];
        float v1 = pairs[1][h * 128 + (t & 63)] * pairs[1][h * 128 + 64 + ((t >> 6) & 63)];
        quads2[k] = make_float2(v0, v1);
    }
    __syncthreads();

    // --- phase 3: evaluate all rules for both rows, track per-thread maxes ---
    const uint4* pk4 = reinterpret_cast<const uint4*>(stream_off);
    const char* qb = (const char*)quads2;
    float mymax0 = -1.0f, mymax1 = -1.0f;
    {
        uint4 bufA = pk4[tid];
        uint4 bufB = pk4[THREADS + tid];
        #pragma unroll
        for (int j = 0; j < ITERS; ++j) {
            uint4 cd = (j & 1) ? bufB : bufA;
            if (j + 2 < ITERS) {
                if (j & 1) bufB = pk4[(j + 2) * THREADS + tid];
                else       bufA = pk4[(j + 2) * THREADS + tid];
            }
            unsigned cods[4] = {cd.x, cd.y, cd.z, cd.w};
            #pragma unroll
            for (int s = 0; s < 4; ++s) {
                unsigned w = cods[s];
                float2 a = *(const float2*)(qb + (w & 0xFFFFu));
                float2 t = *(const float2*)(qb + 32768u + (w >> 16));
                mymax0 = fmaxf(mymax0, a.x * t.x);
                mymax1 = fmaxf(mymax1, a.y * t.y);
            }
        }
    }
    smax2[tid] = make_float2(mymax0, mymax1);
    __syncthreads();

    // --- phase 4: waves 0/1 extract 8th-largest thread max per row ---
    if (tid < 128) {
        int row = tid >> 6, lane = tid & 63;
        float m[16];
        #pragma unroll
        for (int k = 0; k < 16; ++k) {
            float2 s = smax2[lane + 64 * k];
            m[k] = row ? s.y : s.x;
        }
        float thr = -1.0f;
        #pragma unroll
        for (int round = 0; round < 8; ++round) {
            float lm = m[0];
            #pragma unroll
            for (int k = 1; k < 16; ++k) lm = fmaxf(lm, m[k]);
            float wm = lm;
            #pragma unroll
            for (int off = 32; off >= 1; off >>= 1)
                wm = fmaxf(wm, __shfl_xor(wm, off, 64));
            unsigned long long bal = __ballot(lm == wm);
            int first = (int)__ffsll(bal) - 1;
            if (lane == first) {                // remove exactly one instance
                bool done = false;
                #pragma unroll
                for (int k = 0; k < 16; ++k) {
                    bool rm = (!done) && (m[k] == wm);
                    m[k] = rm ? -2.0f : m[k];
                    done = done || rm;
                }
            }
            thr = wm;
        }
        if (lane == 0) sthr[row] = thr;
    }
    __syncthreads();

    // --- phase 5: qualifying threads recompute & push candidates per row ---
    {
        const float thr0 = sthr[0], thr1 = sthr[1];
        if (mymax0 >= thr0 || mymax1 >= thr1) {    // ~16-60 threads of 1024
            for (int j = 0; j < ITERS; ++j) {
                uint4 cd = pk4[j * THREADS + tid];
                unsigned cods[4] = {cd.x, cd.y, cd.z, cd.w};
                #pragma unroll
                for (int s = 0; s < 4; ++s) {
                    unsigned w = cods[s];
                    float2 a = *(const float2*)(qb + (w & 0xFFFFu));
                    float2 t = *(const float2*)(qb + 32768u + (w >> 16));
                    float f0 = a.x * t.x, f1 = a.y * t.y;
                    if (f0 >= thr0) {
                        int flat = (j * THREADS + tid) * 4 + s;
                        int pos = atomicAdd(&scnt[0], 1);
                        if (pos < CAP) { cvals[0][pos] = f0; cidx[0][pos] = g_sidx[flat]; }
                    }
                    if (f1 >= thr1) {
                        int flat = (j * THREADS + tid) * 4 + s;
                        int pos = atomicAdd(&scnt[1], 1);
                        if (pos < CAP) { cvals[1][pos] = f1; cidx[1][pos] = g_sidx[flat]; }
                    }
                }
            }
        }
    }
    __syncthreads();

    // --- phase 6: exact rank selection per row (val desc, orig idx asc) ---
    if (tid < 128) {
        int row = tid >> 6, lane = tid & 63;
        int n = scnt[row] < CAP ? scnt[row] : CAP;
        for (int c = lane; c < n; c += 64) {
            float v  = cvals[row][c];
            int   id = cidx[row][c];
            int rk = 0;
            for (int mI = 0; mI < n; ++mI) {
                float vm = cvals[row][mI];
                int   im = cidx[row][mI];
                rk += ((vm > v) || (vm == v && im < id)) ? 1 : 0;
            }
            if (rk < 8) {
                wv[row][rk] = v;
                wc[row][rk] = consequents[id];
            }
        }
    }
    __syncthreads();

    // --- phase 7: defuzzify (one thread per row) ---
    if (tid == 0 || tid == 64) {
        int row = tid >> 6;
        float num = 0.0f, den = 0.0f;
        #pragma unroll
        for (int k = 0; k < 8; ++k) {
            num += wv[row][k] * s1s[wc[row][k]];
            den += wv[row][k] * s0s[wc[row][k]];
        }
        out[b0 + row] = num / (den + EPSF);
    }
}

// ---------------- generic fallback (round-1 kernel, inline pack) ------------
__global__ __launch_bounds__(256) void anfis_kernel(
    const float* __restrict__ x,
    const int* __restrict__ ant,
    const int* __restrict__ consequents,
    const float* __restrict__ in_centers,
    const float* __restrict__ in_widths,
    const float* __restrict__ out_centers,
    const float* __restrict__ out_widths,
    float* __restrict__ out,
    int R)
{
    __shared__ float mu[64];
    __shared__ float pairs[256];
    __shared__ float s0s[MOO], s1s[MOO];
    __shared__ float svals[256][9];
    __shared__ int   sidx[256][9];

    const int tid = threadIdx.x;
    const int b   = blockIdx.x;

    if (tid < 64) {
        int d = tid >> 3, c = tid & 7;
        float v = 1.0f;
        if (c < MM) {
            float z = (x[b * DD + d] - in_centers[d * MM + c]) / in_widths[d * MM + c];
            v = expf(-0.5f * z * z);
            v = fminf(v, 1.0f);
            v = fmaxf(v, EPSF);
        }
        mu[tid] = v;
    } else if (tid < 64 + MOO) {
        int mo = tid - 64;
        float oc = out_centers[mo], ow = out_widths[mo];
        float s0 = 0.0f, s1 = 0.0f;
        for (int p = 0; p < NPTS; ++p) {
            float u = (float)p * (1.0f / 99.0f);
            float z = (u - oc) / ow;
            float e = expf(-0.5f * z * z);
            s0 += e;
            s1 += u * e;
        }
        s0s[mo] = s0;
        s1s[mo] = s1;
    }
    __syncthreads();

    {
        int p = tid >> 6, q = tid & 63;
        pairs[tid] = mu[(2 * p) * 8 + (q & 7)] * mu[(2 * p + 1) * 8 + (q >> 3)];
    }
    __syncthreads();

    float vals[8];
    int   idxs[8];
    #pragma unroll
    for (int k = 0; k < 8; ++k) { vals[k] = -1.0f; idxs[k] = 0x7fffffff; }

    for (int r = tid; r < R; r += 256) {
        const int4* a = reinterpret_cast<const int4*>(ant) + (size_t)r * 2;
        int4 lo = a[0], hi = a[1];
        int v[8] = {lo.x, lo.y, lo.z, lo.w, hi.x, hi.y, hi.z, hi.w};
        unsigned code = 0u;
        #pragma unroll
        for (int i = 0; i < 8; ++i) {
            int c = v[i];
            c = (c < 0) ? 7 : (c > MM - 1 ? MM - 1 : c);
            code |= (unsigned)c << (3 * i);
        }
        float f = pairs[code & 63]
                * pairs[64  + ((code >> 6)  & 63)]
                * pairs[128 + ((code >> 12) & 63)]
                * pairs[192 + ((code >> 18) & 63)];
        if (f > vals[7]) {
            float nv = f; int ni = r;
            #pragma unroll
            for (int k = 0; k < 8; ++k) {
                bool take = nv > vals[k];
                float cv = vals[k]; int ci = idxs[k];
                vals[k] = take ? nv : cv;
                idxs[k] = take ? ni : ci;
                nv = take ? cv : nv;
                ni = take ? ci : ni;
            }
        }
    }

    #pragma unroll
    for (int k = 0; k < 8; ++k) { svals[tid][k] = vals[k]; sidx[tid][k] = idxs[k]; }

    for (int off = 128; off >= 1; off >>= 1) {
        __syncthreads();
        if (tid < off) {
            float ov[8]; int oi[8];
            int pa = 0, pb = 0;
            #pragma unroll
            for (int k = 0; k < 8; ++k) {
                float va = svals[tid][pa];        int ia = sidx[tid][pa];
                float vb = svals[tid + off][pb];  int ib = sidx[tid + off][pb];
                bool ta = (va > vb) || ((va == vb) && (ia < ib));
                ov[k] = ta ? va : vb;
                oi[k] = ta ? ia : ib;
                pa += ta ? 1 : 0;
                pb += ta ? 0 : 1;
            }
            #pragma unroll
            for (int k = 0; k < 8; ++k) { svals[tid][k] = ov[k]; sidx[tid][k] = oi[k]; }
        }
    }
    __syncthreads();

    if (tid == 0) {
        float num = 0.0f, den = 0.0f;
        #pragma unroll
        for (int k = 0; k < 8; ++k) {
            float v = svals[0][k];
            int   c = consequents[sidx[0][k]];
            num += v * s1s[c];
            den += v * s0s[c];
        }
        out[b] = num / (den + EPSF);
    }
}

extern "C" void kernel_launch(void* const* d_in, const int* in_sizes, int n_in,
                              void* d_out, int out_size, void* d_ws, size_t ws_size,
                              hipStream_t stream) {
    const float* x      = (const float*)d_in[0];
    const int*   ant    = (const int*)d_in[1];
    const int*   cons   = (const int*)d_in[2];
    const float* in_c   = (const float*)d_in[3];
    const float* in_w   = (const float*)d_in[4];
    const float* out_c  = (const float*)d_in[5];
    const float* out_w  = (const float*)d_in[6];
    float*       out    = (float*)d_out;

    const int B = in_sizes[0] / DD;
    const int R = in_sizes[1] / DD;

    const bool shape_ok = (R == THREADS * 4 * ITERS) && (B % 2 == 0);
    const size_t need = (size_t)R * 12 + (size_t)NBUCK * 4;    // off+soff+sidx+hist

    if (shape_ok && d_ws && ws_size >= need) {
        unsigned* g_off  = (unsigned*)d_ws;
        unsigned* g_soff = g_off + R;
        int*      g_sidx = (int*)(g_soff + R);
        unsigned* g_hist = (unsigned*)(g_sidx + R);
        hipMemsetAsync(g_hist, 0, NBUCK * sizeof(unsigned), stream);
        pack_hist_kernel<<<(R + 255) / 256, 256, 0, stream>>>(ant, g_off, g_hist, R);
        scan_kernel<<<1, 1024, 0, stream>>>(g_hist);
        scatter_kernel<<<(R + 255) / 256, 256, 0, stream>>>(g_off, g_hist, g_soff, g_sidx, R);
        anfis2<<<B / 2, THREADS, 0, stream>>>(x, g_soff, g_sidx, cons,
                                              in_c, in_w, out_c, out_w, out);
    } else {
        anfis_kernel<<<B, 256, 0, stream>>>(x, ant, cons, in_c, in_w,
                                            out_c, out_w, out, R);
    }
}